// Round 10
// baseline (431.342 us; speedup 1.0000x reference)
//
#include <hip/hip_runtime.h>
#include <hip/hip_bf16.h>

#define N_NODES_C 100000
#define N_EDGES_C 150000
#define DC 512
#define NG 64

typedef float f32x4 __attribute__((ext_vector_type(4)));
typedef short s16x8 __attribute__((ext_vector_type(8)));
typedef unsigned int u32;

__device__ __forceinline__ short f2bf(float f) {
    union { float f; unsigned u; } c; c.f = f;
    unsigned r = c.u + 0x7fffu + ((c.u >> 16) & 1u);
    return (short)(r >> 16);
}
__device__ __forceinline__ float bf2f(short v) {
    union { unsigned u; float f; } c;
    c.u = ((unsigned)(unsigned short)v) << 16;
    return c.f;
}

// async global->LDS, 16B per lane; LDS dest is wave-uniform base + lane*16
__device__ __forceinline__ void gload16(const void* g, void* l) {
    __builtin_amdgcn_global_load_lds((const __attribute__((address_space(1))) u32*)g,
                                     (__attribute__((address_space(3))) u32*)l,
                                     16, 0, 0);
}

// ---------------- small kernels ----------------

__global__ void zero_k(float* s, float* aggs, int* cnt, float* gsum, float* gcnt) {
    int i = blockIdx.x * 256 + threadIdx.x;
    if (i < N_NODES_C) { s[i] = 0.f; aggs[i] = 0.f; cnt[i] = 0; }
    if (i < NG) { gsum[i] = 0.f; gcnt[i] = 0.f; }
}

// out[n][k] = bf16(in[k][n]); in is [512][512] f32 row-major
__global__ void transpose_w(const float* __restrict__ in, short* __restrict__ out) {
    __shared__ float tile[32][33];
    int tx = threadIdx.x & 31;
    int ty = threadIdx.x >> 5;  // 0..7
    int k0 = blockIdx.y * 32;
    int n0 = blockIdx.x * 32;
#pragma unroll
    for (int i = 0; i < 4; ++i)
        tile[ty + i * 8][tx] = in[(size_t)(k0 + ty + i * 8) * DC + n0 + tx];
    __syncthreads();
#pragma unroll
    for (int i = 0; i < 4; ++i)
        out[(size_t)(n0 + ty + i * 8) * DC + k0 + tx] = f2bf(tile[tx][ty + i * 8]);
}

// ---------------- counting sort of edges by dst ----------------

__global__ void hist_k(const int* __restrict__ ei, int* __restrict__ cnt) {
    int e = blockIdx.x * 256 + threadIdx.x;
    if (e < N_EDGES_C) atomicAdd(&cnt[ei[N_EDGES_C + e]], 1);
}

__global__ void scan1_k(const int* __restrict__ cnt, int* __restrict__ off,
                        int* __restrict__ bsum) {
    __shared__ int sh[1024];
    int tid = threadIdx.x;
    int i = blockIdx.x * 1024 + tid;
    int v = (i < N_NODES_C) ? cnt[i] : 0;
    sh[tid] = v;
    __syncthreads();
    for (int d = 1; d < 1024; d <<= 1) {
        int t = (tid >= d) ? sh[tid - d] : 0;
        __syncthreads();
        sh[tid] += t;
        __syncthreads();
    }
    if (i < N_NODES_C) off[i] = sh[tid] - v;  // exclusive
    if (tid == 1023) bsum[blockIdx.x] = sh[1023];
}

#define NSCAN_BLK 98  // ceil(100000/1024)

__global__ void scan2_k(int* __restrict__ bsum) {
    __shared__ int sh[128];
    int tid = threadIdx.x;
    int v = (tid < NSCAN_BLK) ? bsum[tid] : 0;
    sh[tid] = v;
    __syncthreads();
    for (int d = 1; d < 128; d <<= 1) {
        int t = (tid >= d) ? sh[tid - d] : 0;
        __syncthreads();
        sh[tid] += t;
        __syncthreads();
    }
    if (tid < NSCAN_BLK) bsum[tid] = sh[tid] - v;  // exclusive
}

__global__ void scan3_k(int* __restrict__ off, const int* __restrict__ bsum) {
    int i = blockIdx.x * 1024 + threadIdx.x;
    if (i < N_NODES_C) off[i] += bsum[blockIdx.x];
}

// place: off becomes end-cursor; after completion off[i] = start of node i+1
__global__ void place_k(const int* __restrict__ ei, int* __restrict__ off,
                        int* __restrict__ ssrc) {
    int e = blockIdx.x * 256 + threadIdx.x;
    if (e < N_EDGES_C) {
        int d = ei[N_EDGES_C + e];
        int p = atomicAdd(&off[d], 1);
        ssrc[p] = ei[e];
    }
}

// z1[i] = bf16(relu(y[i] + sum_{e:dst=i} y[src_e] + b1a)); 4 nodes/block, 64 lanes/node
__global__ void gather_relu_k(const short* __restrict__ y, const int* __restrict__ off,
                              const int* __restrict__ ssrc, const float* __restrict__ b1a,
                              short* __restrict__ z1) {
    int node = blockIdx.x * 4 + (threadIdx.x >> 6);
    if (node >= N_NODES_C) return;
    int t = threadIdx.x & 63;
    const int col = t * 8;
    int beg = (node == 0) ? 0 : off[node - 1];
    int end = off[node];
    s16x8 own = *(const s16x8*)(y + (size_t)node * DC + col);
    float acc[8];
#pragma unroll
    for (int q = 0; q < 8; ++q) acc[q] = bf2f(own[q]);
    int j = beg;
    for (; j + 2 <= end; j += 2) {
        int s0 = ssrc[j];
        int s1 = ssrc[j + 1];
        s16x8 r0 = *(const s16x8*)(y + (size_t)s0 * DC + col);
        s16x8 r1 = *(const s16x8*)(y + (size_t)s1 * DC + col);
#pragma unroll
        for (int q = 0; q < 8; ++q) acc[q] += bf2f(r0[q]) + bf2f(r1[q]);
    }
    if (j < end) {
        int s0 = ssrc[j];
        s16x8 r0 = *(const s16x8*)(y + (size_t)s0 * DC + col);
#pragma unroll
        for (int q = 0; q < 8; ++q) acc[q] += bf2f(r0[q]);
    }
    f32x4 bv0 = *(const f32x4*)(b1a + col);
    f32x4 bv1 = *(const f32x4*)(b1a + col + 4);
    s16x8 o;
    o[0] = f2bf(fmaxf(acc[0] + bv0.x, 0.f));
    o[1] = f2bf(fmaxf(acc[1] + bv0.y, 0.f));
    o[2] = f2bf(fmaxf(acc[2] + bv0.z, 0.f));
    o[3] = f2bf(fmaxf(acc[3] + bv0.w, 0.f));
    o[4] = f2bf(fmaxf(acc[4] + bv1.x, 0.f));
    o[5] = f2bf(fmaxf(acc[5] + bv1.y, 0.f));
    o[6] = f2bf(fmaxf(acc[6] + bv1.z, 0.f));
    o[7] = f2bf(fmaxf(acc[7] + bv1.w, 0.f));
    *(s16x8*)(z1 + (size_t)node * DC + col) = o;
}

// ---------------- scalar tail ----------------

__global__ void edge_scalar(const int* __restrict__ ei, const float* __restrict__ s,
                            float* __restrict__ aggs) {
    int e = blockIdx.x * 256 + threadIdx.x;
    if (e < N_EDGES_C) atomicAdd(&aggs[ei[N_EDGES_C + e]], s[ei[e]]);
}

__global__ void node_pool(const float* __restrict__ s, const float* __restrict__ aggs,
                          const int* __restrict__ batch, const float* __restrict__ b2a,
                          float* __restrict__ gsum, float* __restrict__ gcnt) {
    __shared__ float ls[NG], lc[NG];
    int t = threadIdx.x;
    if (t < NG) { ls[t] = 0.f; lc[t] = 0.f; }
    __syncthreads();
    int i = blockIdx.x * 256 + t;
    if (i < N_NODES_C) {
        float z2 = fmaxf(aggs[i] + s[i] + b2a[0], 0.0f);
        int g = batch[i];
        atomicAdd(&ls[g], z2);
        atomicAdd(&lc[g], 1.0f);
    }
    __syncthreads();
    if (t < NG && lc[t] != 0.f) {
        atomicAdd(&gsum[t], ls[t]);
        atomicAdd(&gcnt[t], lc[t]);
    }
}

__global__ void finalize_k(const float* gsum, const float* gcnt, const float* w2b,
                           const float* b2b, float* out) {
    int g = threadIdx.x;
    if (g < NG) {
        float c = fmaxf(gcnt[g], 1.0f);
        out[g] = gsum[g] / c * w2b[0] + b2b[0];
    }
}

// ---------------- GEMM ----------------
// 128x128 tile, BK=64 (8 K-iters -> half the barrier drains of BK=32),
// single-buffered 32KB LDS (~4-5 blocks/CU static), XOR chunk-swizzle
// (chunk ^= row&7; round-9-verified conflict-free) applied source-side for
// gload_lds / write-side for the f32 path, matched on frag ds_reads.
// ASRC 0: A f32, reg-staged + fused f32->bf16 (next-tile loads issued after
//         barrier2, landing under the 32-MFMA block).
// ASRC 1: A bf16 via global_load_lds.
// EPI 1: h = relu(A@W + bias); s_out[row] += h . w2a
// EPI 2: C = A@W -> bf16
#define BM 128
#define BN 128
#define BK 64
#define NKT (DC / BK)  // 8
#define NWG 3128       // 782 row tiles * 4 col tiles = 8 * 391
#define WPX 391

template <int ASRC, int EPI>
__global__ __launch_bounds__(256, 4) void gemm_k(const void* __restrict__ Ap,
                                                 const short* __restrict__ Bt,
                                                 const float* __restrict__ bias,
                                                 short* __restrict__ Cout,
                                                 const float* __restrict__ w2a,
                                                 float* __restrict__ s_out) {
    __shared__ alignas(16) short As[BM * BK];  // 16 KB
    __shared__ alignas(16) short Bs[BN * BK];  // 16 KB

    const int tid = threadIdx.x;
    // XCD-aware bijective remap: 3128 = 8*391
    const int bid = blockIdx.x;
    const int lin = (bid & 7) * WPX + (bid >> 3);
    const int brow = (lin >> 2) * BM;
    const int bcol = (lin & 3) * BN;

    const int w    = tid >> 6;       // wave 0..3
    const int lane = tid & 63;
    const int wr   = (w >> 1) * 64;  // wave row
    const int wc   = (w & 1) * 64;   // wave col
    const int lr   = lane & 15;
    const int lg   = lane >> 4;      // 0..3: K-chunk group within 32-K slab

    f32x4 acc[4][4] = {};

    // ---- staging geometry (row of 64 shorts = 8 chunks of 8 shorts) ----
    const int l8 = lane >> 3;                 // row within 8-row group
    const int scs = ((lane & 7) ^ l8) * 8;    // swizzled source chunk (shorts)

    // B: wave w stages rows bcol + w*32 + j*8 + l8, j=0..3
    const short* bsrc = Bt + (size_t)(bcol + w * 32 + l8) * DC + scs;
    // A (ASRC 1)
    const short* asrc[4];
    // A (ASRC 0)
    const float* axsrc = nullptr;
    int awoff[4];
    const int rAl = tid >> 1;        // LDS row this thread stages (0..127)
    if constexpr (ASRC == 1) {
#pragma unroll
        for (int j = 0; j < 4; ++j) {
            int r = brow + w * 32 + j * 8 + l8;
            if (r >= N_NODES_C) r = N_NODES_C - 1;  // clamp; stores guarded
            asrc[j] = (const short*)Ap + (size_t)r * DC + scs;
        }
    } else {
        int r = brow + rAl;
        if (r >= N_NODES_C) r = N_NODES_C - 1;
        axsrc = (const float*)Ap + (size_t)r * DC + (tid & 1) * 32;
#pragma unroll
        for (int j = 0; j < 4; ++j)
            awoff[j] = rAl * BK + ((((tid & 1) * 4 + j) ^ (rAl & 7)) * 8);
    }

    f32x4 areg[8];
    if constexpr (ASRC == 0) {
#pragma unroll
        for (int q = 0; q < 8; ++q) areg[q] = *(const f32x4*)(axsrc + q * 4);  // tile 0
    }

    for (int kt = 0; kt < NKT; ++kt) {
        const int k0 = kt * BK;
        __syncthreads();  // all waves done reading LDS from previous tile
        if constexpr (ASRC == 1) {
#pragma unroll
            for (int j = 0; j < 4; ++j)
                gload16(asrc[j] + j * 8 * DC + k0, &As[(w * 32 + j * 8) * BK]);
        } else {
#pragma unroll
            for (int j = 0; j < 4; ++j) {
                s16x8 c;
                c[0] = f2bf(areg[2 * j].x);     c[1] = f2bf(areg[2 * j].y);
                c[2] = f2bf(areg[2 * j].z);     c[3] = f2bf(areg[2 * j].w);
                c[4] = f2bf(areg[2 * j + 1].x); c[5] = f2bf(areg[2 * j + 1].y);
                c[6] = f2bf(areg[2 * j + 1].z); c[7] = f2bf(areg[2 * j + 1].w);
                *(s16x8*)&As[awoff[j]] = c;
            }
        }
#pragma unroll
        for (int j = 0; j < 4; ++j)
            gload16(bsrc + j * 8 * DC + k0, &Bs[(w * 32 + j * 8) * BK]);
        __syncthreads();  // drains vmcnt+lgkmcnt: tile kt fully in LDS

        if constexpr (ASRC == 0) {
            if (kt + 1 < NKT) {  // next f32 A slab: lands during MFMA below
#pragma unroll
                for (int q = 0; q < 8; ++q)
                    areg[q] = *(const f32x4*)(axsrc + (kt + 1) * BK + q * 4);
            }
        }

#pragma unroll
        for (int kk = 0; kk < 2; ++kk) {
            s16x8 af[4], bfr[4];
#pragma unroll
            for (int mi = 0; mi < 4; ++mi)
                af[mi] = *(const s16x8*)&As[(wr + mi * 16 + lr) * BK +
                                            (((kk * 4 + lg) ^ (lr & 7)) * 8)];
#pragma unroll
            for (int ni = 0; ni < 4; ++ni)
                bfr[ni] = *(const s16x8*)&Bs[(wc + ni * 16 + lr) * BK +
                                             (((kk * 4 + lg) ^ (lr & 7)) * 8)];
            __builtin_amdgcn_s_setprio(1);
#pragma unroll
            for (int mi = 0; mi < 4; ++mi)
#pragma unroll
                for (int ni = 0; ni < 4; ++ni)
                    acc[mi][ni] = __builtin_amdgcn_mfma_f32_16x16x32_bf16(
                        af[mi], bfr[ni], acc[mi][ni], 0, 0, 0);
            __builtin_amdgcn_s_setprio(0);
        }
    }

    // C/D layout: col = lane&15, row = (lane>>4)*4 + reg
    const int rb = brow + wr + lg * 4;
    const int cb = bcol + wc + lr;

    if constexpr (EPI == 2) {
#pragma unroll
        for (int mi = 0; mi < 4; ++mi) {
#pragma unroll
            for (int r = 0; r < 4; ++r) {
                int row = rb + mi * 16 + r;
                if (row < N_NODES_C) {
#pragma unroll
                    for (int ni = 0; ni < 4; ++ni)
                        Cout[(size_t)row * DC + cb + ni * 16] = f2bf(acc[mi][ni][r]);
                }
            }
        }
    } else {
        float bv[4], wv[4];
#pragma unroll
        for (int ni = 0; ni < 4; ++ni) {
            bv[ni] = bias[cb + ni * 16];
            wv[ni] = w2a[cb + ni * 16];
        }
#pragma unroll
        for (int mi = 0; mi < 4; ++mi) {
#pragma unroll
            for (int r = 0; r < 4; ++r) {
                float sum = 0.f;
#pragma unroll
                for (int ni = 0; ni < 4; ++ni) {
                    float v = fmaxf(acc[mi][ni][r] + bv[ni], 0.0f);
                    sum += v * wv[ni];
                }
#pragma unroll
                for (int off = 1; off < 16; off <<= 1) sum += __shfl_xor(sum, off, 64);
                int row = rb + mi * 16 + r;
                if (lr == 0 && row < N_NODES_C) atomicAdd(&s_out[row], sum);
            }
        }
    }
}

// ---------------- launch ----------------

extern "C" void kernel_launch(void* const* d_in, const int* in_sizes, int n_in,
                              void* d_out, int out_size, void* d_ws, size_t ws_size,
                              hipStream_t stream) {
    const float* x     = (const float*)d_in[0];
    const int*   ei    = (const int*)d_in[1];
    const int*   batch = (const int*)d_in[2];
    const float* W1a   = (const float*)d_in[3];
    const float* b1a   = (const float*)d_in[4];
    const float* W1b   = (const float*)d_in[5];
    const float* b1b   = (const float*)d_in[6];
    const float* W2a   = (const float*)d_in[7];
    const float* b2a   = (const float*)d_in[8];
    const float* W2b   = (const float*)d_in[9];
    const float* b2b   = (const float*)d_in[10];
    float* out = (float*)d_out;

    char* w = (char*)d_ws;
    short* z1   = (short*)(w);                  // 102,400,000
    short* y    = (short*)(w + 102400000);      // 102,400,000
    short* WT1  = (short*)(w + 204800000);      // 524,288
    short* WT2  = (short*)(w + 205324288);      // 524,288
    float* sbuf = (float*)(w + 205848576);      // 400,000
    float* aggs = (float*)(w + 206248576);      // 400,000
    int*   cnt  = (int*)  (w + 206648576);      // 400,000
    int*   offb = (int*)  (w + 207048576);      // 400,000
    int*   ssrc = (int*)  (w + 207448576);      // 600,000
    int*   bsum = (int*)  (w + 208048576);      // 512
    float* gsum = (float*)(w + 208049088);      // 256
    float* gcnt = (float*)(w + 208049344);      // 256

    zero_k<<<391, 256, 0, stream>>>(sbuf, aggs, cnt, gsum, gcnt);
    transpose_w<<<dim3(16, 16), 256, 0, stream>>>(W1a, WT1);
    transpose_w<<<dim3(16, 16), 256, 0, stream>>>(W1b, WT2);

    // CSR build (independent of GEMM0)
    hist_k<<<586, 256, 0, stream>>>(ei, cnt);
    scan1_k<<<NSCAN_BLK, 1024, 0, stream>>>(cnt, offb, bsum);
    scan2_k<<<1, 128, 0, stream>>>(bsum);
    scan3_k<<<NSCAN_BLK, 1024, 0, stream>>>(offb, bsum);
    place_k<<<586, 256, 0, stream>>>(ei, offb, ssrc);

    // y = bf16(x) @ W1a  (f32 A, fused convert in staging)
    gemm_k<0, 2><<<NWG, 256, 0, stream>>>(x, WT1, nullptr, y, nullptr, nullptr);
    // z1 = relu(y + agg(y) + b1a)
    gather_relu_k<<<25000, 256, 0, stream>>>(y, offb, ssrc, b1a, z1);
    // s = relu(z1 @ W1b + b1b) . W2a
    gemm_k<1, 1><<<NWG, 256, 0, stream>>>(z1, WT2, b1b, nullptr, W2a, sbuf);

    edge_scalar<<<586, 256, 0, stream>>>(ei, sbuf, aggs);
    node_pool<<<391, 256, 0, stream>>>(sbuf, aggs, batch, b2a, gsum, gcnt);
    finalize_k<<<1, 64, 0, stream>>>(gsum, gcnt, W2b, b2b, out);
}

// Round 11
// 312.599 us; speedup vs baseline: 1.3799x; 1.3799x over previous
//
#include <hip/hip_runtime.h>
#include <hip/hip_bf16.h>

#define N_NODES_C 100000
#define N_EDGES_C 150000
#define DC 512
#define NG 64

typedef float f32x4 __attribute__((ext_vector_type(4)));
typedef short s16x8 __attribute__((ext_vector_type(8)));
typedef unsigned int u32;

__device__ __forceinline__ short f2bf(float f) {
    union { float f; unsigned u; } c; c.f = f;
    unsigned r = c.u + 0x7fffu + ((c.u >> 16) & 1u);
    return (short)(r >> 16);
}
__device__ __forceinline__ float bf2f(short v) {
    union { unsigned u; float f; } c;
    c.u = ((unsigned)(unsigned short)v) << 16;
    return c.f;
}

// async global->LDS, 16B per lane; LDS dest is wave-uniform base + lane*16
__device__ __forceinline__ void gload16(const void* g, void* l) {
    __builtin_amdgcn_global_load_lds((const __attribute__((address_space(1))) u32*)g,
                                     (__attribute__((address_space(3))) u32*)l,
                                     16, 0, 0);
}

// ---------------- small kernels ----------------

__global__ void zero_k(float* s, float* aggs, int* cnt, float* gsum, float* gcnt) {
    int i = blockIdx.x * 256 + threadIdx.x;
    if (i < N_NODES_C) { s[i] = 0.f; aggs[i] = 0.f; cnt[i] = 0; }
    if (i < NG) { gsum[i] = 0.f; gcnt[i] = 0.f; }
}

// out[n][k] = bf16(in[k][n]); in is [512][512] f32 row-major
__global__ void transpose_w(const float* __restrict__ in, short* __restrict__ out) {
    __shared__ float tile[32][33];
    int tx = threadIdx.x & 31;
    int ty = threadIdx.x >> 5;  // 0..7
    int k0 = blockIdx.y * 32;
    int n0 = blockIdx.x * 32;
#pragma unroll
    for (int i = 0; i < 4; ++i)
        tile[ty + i * 8][tx] = in[(size_t)(k0 + ty + i * 8) * DC + n0 + tx];
    __syncthreads();
#pragma unroll
    for (int i = 0; i < 4; ++i)
        out[(size_t)(n0 + ty + i * 8) * DC + k0 + tx] = f2bf(tile[tx][ty + i * 8]);
}

// ---------------- counting sort of edges by dst ----------------

__global__ void hist_k(const int* __restrict__ ei, int* __restrict__ cnt) {
    int e = blockIdx.x * 256 + threadIdx.x;
    if (e < N_EDGES_C) atomicAdd(&cnt[ei[N_EDGES_C + e]], 1);
}

__global__ void scan1_k(const int* __restrict__ cnt, int* __restrict__ off,
                        int* __restrict__ bsum) {
    __shared__ int sh[1024];
    int tid = threadIdx.x;
    int i = blockIdx.x * 1024 + tid;
    int v = (i < N_NODES_C) ? cnt[i] : 0;
    sh[tid] = v;
    __syncthreads();
    for (int d = 1; d < 1024; d <<= 1) {
        int t = (tid >= d) ? sh[tid - d] : 0;
        __syncthreads();
        sh[tid] += t;
        __syncthreads();
    }
    if (i < N_NODES_C) off[i] = sh[tid] - v;  // exclusive
    if (tid == 1023) bsum[blockIdx.x] = sh[1023];
}

#define NSCAN_BLK 98  // ceil(100000/1024)

__global__ void scan2_k(int* __restrict__ bsum) {
    __shared__ int sh[128];
    int tid = threadIdx.x;
    int v = (tid < NSCAN_BLK) ? bsum[tid] : 0;
    sh[tid] = v;
    __syncthreads();
    for (int d = 1; d < 128; d <<= 1) {
        int t = (tid >= d) ? sh[tid - d] : 0;
        __syncthreads();
        sh[tid] += t;
        __syncthreads();
    }
    if (tid < NSCAN_BLK) bsum[tid] = sh[tid] - v;  // exclusive
}

__global__ void scan3_k(int* __restrict__ off, const int* __restrict__ bsum) {
    int i = blockIdx.x * 1024 + threadIdx.x;
    if (i < N_NODES_C) off[i] += bsum[blockIdx.x];
}

// place: off becomes end-cursor; after completion off[i] = start of node i+1
__global__ void place_k(const int* __restrict__ ei, int* __restrict__ off,
                        int* __restrict__ ssrc) {
    int e = blockIdx.x * 256 + threadIdx.x;
    if (e < N_EDGES_C) {
        int d = ei[N_EDGES_C + e];
        int p = atomicAdd(&off[d], 1);
        ssrc[p] = ei[e];
    }
}

// z1[i] = bf16(relu(y[i] + sum_{e:dst=i} y[src_e] + b1a)); 4 nodes/block, 64 lanes/node
__global__ void gather_relu_k(const short* __restrict__ y, const int* __restrict__ off,
                              const int* __restrict__ ssrc, const float* __restrict__ b1a,
                              short* __restrict__ z1) {
    int node = blockIdx.x * 4 + (threadIdx.x >> 6);
    if (node >= N_NODES_C) return;
    int t = threadIdx.x & 63;
    const int col = t * 8;
    int beg = (node == 0) ? 0 : off[node - 1];
    int end = off[node];
    s16x8 own = *(const s16x8*)(y + (size_t)node * DC + col);
    float acc[8];
#pragma unroll
    for (int q = 0; q < 8; ++q) acc[q] = bf2f(own[q]);
    int j = beg;
    for (; j + 2 <= end; j += 2) {
        int s0 = ssrc[j];
        int s1 = ssrc[j + 1];
        s16x8 r0 = *(const s16x8*)(y + (size_t)s0 * DC + col);
        s16x8 r1 = *(const s16x8*)(y + (size_t)s1 * DC + col);
#pragma unroll
        for (int q = 0; q < 8; ++q) acc[q] += bf2f(r0[q]) + bf2f(r1[q]);
    }
    if (j < end) {
        int s0 = ssrc[j];
        s16x8 r0 = *(const s16x8*)(y + (size_t)s0 * DC + col);
#pragma unroll
        for (int q = 0; q < 8; ++q) acc[q] += bf2f(r0[q]);
    }
    f32x4 bv0 = *(const f32x4*)(b1a + col);
    f32x4 bv1 = *(const f32x4*)(b1a + col + 4);
    s16x8 o;
    o[0] = f2bf(fmaxf(acc[0] + bv0.x, 0.f));
    o[1] = f2bf(fmaxf(acc[1] + bv0.y, 0.f));
    o[2] = f2bf(fmaxf(acc[2] + bv0.z, 0.f));
    o[3] = f2bf(fmaxf(acc[3] + bv0.w, 0.f));
    o[4] = f2bf(fmaxf(acc[4] + bv1.x, 0.f));
    o[5] = f2bf(fmaxf(acc[5] + bv1.y, 0.f));
    o[6] = f2bf(fmaxf(acc[6] + bv1.z, 0.f));
    o[7] = f2bf(fmaxf(acc[7] + bv1.w, 0.f));
    *(s16x8*)(z1 + (size_t)node * DC + col) = o;
}

// ---------------- scalar tail ----------------

__global__ void edge_scalar(const int* __restrict__ ei, const float* __restrict__ s,
                            float* __restrict__ aggs) {
    int e = blockIdx.x * 256 + threadIdx.x;
    if (e < N_EDGES_C) atomicAdd(&aggs[ei[N_EDGES_C + e]], s[ei[e]]);
}

__global__ void node_pool(const float* __restrict__ s, const float* __restrict__ aggs,
                          const int* __restrict__ batch, const float* __restrict__ b2a,
                          float* __restrict__ gsum, float* __restrict__ gcnt) {
    __shared__ float ls[NG], lc[NG];
    int t = threadIdx.x;
    if (t < NG) { ls[t] = 0.f; lc[t] = 0.f; }
    __syncthreads();
    int i = blockIdx.x * 256 + t;
    if (i < N_NODES_C) {
        float z2 = fmaxf(aggs[i] + s[i] + b2a[0], 0.0f);
        int g = batch[i];
        atomicAdd(&ls[g], z2);
        atomicAdd(&lc[g], 1.0f);
    }
    __syncthreads();
    if (t < NG && lc[t] != 0.f) {
        atomicAdd(&gsum[t], ls[t]);
        atomicAdd(&gcnt[t], lc[t]);
    }
}

__global__ void finalize_k(const float* gsum, const float* gcnt, const float* w2b,
                           const float* b2b, float* out) {
    int g = threadIdx.x;
    if (g < NG) {
        float c = fmaxf(gcnt[g], 1.0f);
        out[g] = gsum[g] / c * w2b[0] + b2b[0];
    }
}

// ---------------- GEMM ----------------
// 128x128 tile, BK=64 (8 K-iters), single-buffered 32KB LDS, XOR chunk-swizzle
// (chunk ^= row&7; round-9-verified conflict-free; round-10-verified correct).
// __launch_bounds__(256,3): reg budget ~170/wave -> no spills (round-10's
// (256,4) capped at 128 and spilled 415 MB to scratch — the regression).
// ASRC 0: A f32, reg-staged + fused f32->bf16.
// ASRC 1: A bf16 via global_load_lds.
// EPI 1: h = relu(A@W + bias); s_out[row] += h . w2a
// EPI 2: C = A@W -> bf16
#define BM 128
#define BN 128
#define BK 64
#define NKT (DC / BK)  // 8
#define NWG 3128       // 782 row tiles * 4 col tiles = 8 * 391
#define WPX 391

template <int ASRC, int EPI>
__global__ __launch_bounds__(256, 3) void gemm_k(const void* __restrict__ Ap,
                                                 const short* __restrict__ Bt,
                                                 const float* __restrict__ bias,
                                                 short* __restrict__ Cout,
                                                 const float* __restrict__ w2a,
                                                 float* __restrict__ s_out) {
    __shared__ alignas(16) short As[BM * BK];  // 16 KB
    __shared__ alignas(16) short Bs[BN * BK];  // 16 KB

    const int tid = threadIdx.x;
    // XCD-aware bijective remap: 3128 = 8*391
    const int bid = blockIdx.x;
    const int lin = (bid & 7) * WPX + (bid >> 3);
    const int brow = (lin >> 2) * BM;
    const int bcol = (lin & 3) * BN;

    const int w    = tid >> 6;       // wave 0..3
    const int lane = tid & 63;
    const int wr   = (w >> 1) * 64;  // wave row
    const int wc   = (w & 1) * 64;   // wave col
    const int lr   = lane & 15;
    const int lg   = lane >> 4;      // 0..3: K-chunk group within 32-K slab

    f32x4 acc[4][4] = {};

    // ---- staging geometry (row of 64 shorts = 8 chunks of 8 shorts) ----
    const int l8 = lane >> 3;                 // row within 8-row group
    const int scs = ((lane & 7) ^ l8) * 8;    // swizzled source chunk (shorts)

    // B: wave w stages rows bcol + w*32 + j*8 + l8, j=0..3
    const short* bsrc = Bt + (size_t)(bcol + w * 32 + l8) * DC + scs;
    // A (ASRC 1)
    const short* asrc[4];
    // A (ASRC 0)
    const float* axsrc = nullptr;
    int awoff[4];
    const int rAl = tid >> 1;        // LDS row this thread stages (0..127)
    if constexpr (ASRC == 1) {
#pragma unroll
        for (int j = 0; j < 4; ++j) {
            int r = brow + w * 32 + j * 8 + l8;
            if (r >= N_NODES_C) r = N_NODES_C - 1;  // clamp; stores guarded
            asrc[j] = (const short*)Ap + (size_t)r * DC + scs;
        }
    } else {
        int r = brow + rAl;
        if (r >= N_NODES_C) r = N_NODES_C - 1;
        axsrc = (const float*)Ap + (size_t)r * DC + (tid & 1) * 32;
#pragma unroll
        for (int j = 0; j < 4; ++j)
            awoff[j] = rAl * BK + ((((tid & 1) * 4 + j) ^ (rAl & 7)) * 8);
    }

    f32x4 areg[8];
    if constexpr (ASRC == 0) {
#pragma unroll
        for (int q = 0; q < 8; ++q) areg[q] = *(const f32x4*)(axsrc + q * 4);  // tile 0
    }

    for (int kt = 0; kt < NKT; ++kt) {
        const int k0 = kt * BK;
        __syncthreads();  // all waves done reading LDS from previous tile
        if constexpr (ASRC == 1) {
#pragma unroll
            for (int j = 0; j < 4; ++j)
                gload16(asrc[j] + j * 8 * DC + k0, &As[(w * 32 + j * 8) * BK]);
        } else {
#pragma unroll
            for (int j = 0; j < 4; ++j) {
                s16x8 c;
                c[0] = f2bf(areg[2 * j].x);     c[1] = f2bf(areg[2 * j].y);
                c[2] = f2bf(areg[2 * j].z);     c[3] = f2bf(areg[2 * j].w);
                c[4] = f2bf(areg[2 * j + 1].x); c[5] = f2bf(areg[2 * j + 1].y);
                c[6] = f2bf(areg[2 * j + 1].z); c[7] = f2bf(areg[2 * j + 1].w);
                *(s16x8*)&As[awoff[j]] = c;
            }
        }
#pragma unroll
        for (int j = 0; j < 4; ++j)
            gload16(bsrc + j * 8 * DC + k0, &Bs[(w * 32 + j * 8) * BK]);
        __syncthreads();  // drains vmcnt+lgkmcnt: tile kt fully in LDS

        if constexpr (ASRC == 0) {
            if (kt + 1 < NKT) {  // next f32 A slab: lands during MFMA below
#pragma unroll
                for (int q = 0; q < 8; ++q)
                    areg[q] = *(const f32x4*)(axsrc + (kt + 1) * BK + q * 4);
            }
        }

#pragma unroll
        for (int kk = 0; kk < 2; ++kk) {
            s16x8 af[4], bfr[4];
#pragma unroll
            for (int mi = 0; mi < 4; ++mi)
                af[mi] = *(const s16x8*)&As[(wr + mi * 16 + lr) * BK +
                                            (((kk * 4 + lg) ^ (lr & 7)) * 8)];
#pragma unroll
            for (int ni = 0; ni < 4; ++ni)
                bfr[ni] = *(const s16x8*)&Bs[(wc + ni * 16 + lr) * BK +
                                             (((kk * 4 + lg) ^ (lr & 7)) * 8)];
            __builtin_amdgcn_s_setprio(1);
#pragma unroll
            for (int mi = 0; mi < 4; ++mi)
#pragma unroll
                for (int ni = 0; ni < 4; ++ni)
                    acc[mi][ni] = __builtin_amdgcn_mfma_f32_16x16x32_bf16(
                        af[mi], bfr[ni], acc[mi][ni], 0, 0, 0);
            __builtin_amdgcn_s_setprio(0);
        }
    }

    // C/D layout: col = lane&15, row = (lane>>4)*4 + reg
    const int rb = brow + wr + lg * 4;
    const int cb = bcol + wc + lr;

    if constexpr (EPI == 2) {
#pragma unroll
        for (int mi = 0; mi < 4; ++mi) {
#pragma unroll
            for (int r = 0; r < 4; ++r) {
                int row = rb + mi * 16 + r;
                if (row < N_NODES_C) {
#pragma unroll
                    for (int ni = 0; ni < 4; ++ni)
                        Cout[(size_t)row * DC + cb + ni * 16] = f2bf(acc[mi][ni][r]);
                }
            }
        }
    } else {
        float bv[4], wv[4];
#pragma unroll
        for (int ni = 0; ni < 4; ++ni) {
            bv[ni] = bias[cb + ni * 16];
            wv[ni] = w2a[cb + ni * 16];
        }
#pragma unroll
        for (int mi = 0; mi < 4; ++mi) {
#pragma unroll
            for (int r = 0; r < 4; ++r) {
                float sum = 0.f;
#pragma unroll
                for (int ni = 0; ni < 4; ++ni) {
                    float v = fmaxf(acc[mi][ni][r] + bv[ni], 0.0f);
                    sum += v * wv[ni];
                }
#pragma unroll
                for (int off = 1; off < 16; off <<= 1) sum += __shfl_xor(sum, off, 64);
                int row = rb + mi * 16 + r;
                if (lr == 0 && row < N_NODES_C) atomicAdd(&s_out[row], sum);
            }
        }
    }
}

// ---------------- launch ----------------

extern "C" void kernel_launch(void* const* d_in, const int* in_sizes, int n_in,
                              void* d_out, int out_size, void* d_ws, size_t ws_size,
                              hipStream_t stream) {
    const float* x     = (const float*)d_in[0];
    const int*   ei    = (const int*)d_in[1];
    const int*   batch = (const int*)d_in[2];
    const float* W1a   = (const float*)d_in[3];
    const float* b1a   = (const float*)d_in[4];
    const float* W1b   = (const float*)d_in[5];
    const float* b1b   = (const float*)d_in[6];
    const float* W2a   = (const float*)d_in[7];
    const float* b2a   = (const float*)d_in[8];
    const float* W2b   = (const float*)d_in[9];
    const float* b2b   = (const float*)d_in[10];
    float* out = (float*)d_out;

    char* w = (char*)d_ws;
    short* z1   = (short*)(w);                  // 102,400,000
    short* y    = (short*)(w + 102400000);      // 102,400,000
    short* WT1  = (short*)(w + 204800000);      // 524,288
    short* WT2  = (short*)(w + 205324288);      // 524,288
    float* sbuf = (float*)(w + 205848576);      // 400,000
    float* aggs = (float*)(w + 206248576);      // 400,000
    int*   cnt  = (int*)  (w + 206648576);      // 400,000
    int*   offb = (int*)  (w + 207048576);      // 400,000
    int*   ssrc = (int*)  (w + 207448576);      // 600,000
    int*   bsum = (int*)  (w + 208048576);      // 512
    float* gsum = (float*)(w + 208049088);      // 256
    float* gcnt = (float*)(w + 208049344);      // 256

    zero_k<<<391, 256, 0, stream>>>(sbuf, aggs, cnt, gsum, gcnt);
    transpose_w<<<dim3(16, 16), 256, 0, stream>>>(W1a, WT1);
    transpose_w<<<dim3(16, 16), 256, 0, stream>>>(W1b, WT2);

    // CSR build (independent of GEMM0)
    hist_k<<<586, 256, 0, stream>>>(ei, cnt);
    scan1_k<<<NSCAN_BLK, 1024, 0, stream>>>(cnt, offb, bsum);
    scan2_k<<<1, 128, 0, stream>>>(bsum);
    scan3_k<<<NSCAN_BLK, 1024, 0, stream>>>(offb, bsum);
    place_k<<<586, 256, 0, stream>>>(ei, offb, ssrc);

    // y = bf16(x) @ W1a  (f32 A, fused convert in staging)
    gemm_k<0, 2><<<NWG, 256, 0, stream>>>(x, WT1, nullptr, y, nullptr, nullptr);
    // z1 = relu(y + agg(y) + b1a)
    gather_relu_k<<<25000, 256, 0, stream>>>(y, offb, ssrc, b1a, z1);
    // s = relu(z1 @ W1b + b1b) . W2a
    gemm_k<1, 1><<<NWG, 256, 0, stream>>>(z1, WT2, b1b, nullptr, W2a, sbuf);

    edge_scalar<<<586, 256, 0, stream>>>(ei, sbuf, aggs);
    node_pool<<<391, 256, 0, stream>>>(sbuf, aggs, batch, b2a, gsum, gcnt);
    finalize_k<<<1, 64, 0, stream>>>(gsum, gcnt, W2b, b2b, out);
}

// Round 12
// 294.335 us; speedup vs baseline: 1.4655x; 1.0621x over previous
//
#include <hip/hip_runtime.h>
#include <hip/hip_bf16.h>

#define N_NODES_C 100000
#define N_EDGES_C 150000
#define DC 512
#define NG 64

typedef float f32x4 __attribute__((ext_vector_type(4)));
typedef short s16x8 __attribute__((ext_vector_type(8)));
typedef unsigned int u32;

__device__ __forceinline__ short f2bf(float f) {
    union { float f; unsigned u; } c; c.f = f;
    unsigned r = c.u + 0x7fffu + ((c.u >> 16) & 1u);
    return (short)(r >> 16);
}
__device__ __forceinline__ float bf2f(short v) {
    union { unsigned u; float f; } c;
    c.u = ((unsigned)(unsigned short)v) << 16;
    return c.f;
}

// async global->LDS, 16B per lane; LDS dest is wave-uniform base + lane*16
__device__ __forceinline__ void gload16(const void* g, void* l) {
    __builtin_amdgcn_global_load_lds((const __attribute__((address_space(1))) u32*)g,
                                     (__attribute__((address_space(3))) u32*)l,
                                     16, 0, 0);
}

// ---------------- small kernels ----------------

__global__ void zero_k(float* s, float* aggs, int* cnt, float* gsum, float* gcnt) {
    int i = blockIdx.x * 256 + threadIdx.x;
    if (i < N_NODES_C) { s[i] = 0.f; aggs[i] = 0.f; cnt[i] = 0; }
    if (i < NG) { gsum[i] = 0.f; gcnt[i] = 0.f; }
}

// out[n][k] = bf16(in[k][n]); both weights in one launch (blockIdx.z selects)
__global__ void transpose_w2(const float* __restrict__ in0, const float* __restrict__ in1,
                             short* __restrict__ out0, short* __restrict__ out1) {
    __shared__ float tile[32][33];
    const float* in = blockIdx.z ? in1 : in0;
    short* out = blockIdx.z ? out1 : out0;
    int tx = threadIdx.x & 31;
    int ty = threadIdx.x >> 5;  // 0..7
    int k0 = blockIdx.y * 32;
    int n0 = blockIdx.x * 32;
#pragma unroll
    for (int i = 0; i < 4; ++i)
        tile[ty + i * 8][tx] = in[(size_t)(k0 + ty + i * 8) * DC + n0 + tx];
    __syncthreads();
#pragma unroll
    for (int i = 0; i < 4; ++i)
        out[(size_t)(n0 + ty + i * 8) * DC + k0 + tx] = f2bf(tile[tx][ty + i * 8]);
}

// ---------------- counting sort of edges by dst ----------------

__global__ void hist_k(const int* __restrict__ ei, int* __restrict__ cnt) {
    int e = blockIdx.x * 256 + threadIdx.x;
    if (e < N_EDGES_C) atomicAdd(&cnt[ei[N_EDGES_C + e]], 1);
}

__global__ void scan1_k(const int* __restrict__ cnt, int* __restrict__ off,
                        int* __restrict__ bsum) {
    __shared__ int sh[1024];
    int tid = threadIdx.x;
    int i = blockIdx.x * 1024 + tid;
    int v = (i < N_NODES_C) ? cnt[i] : 0;
    sh[tid] = v;
    __syncthreads();
    for (int d = 1; d < 1024; d <<= 1) {
        int t = (tid >= d) ? sh[tid - d] : 0;
        __syncthreads();
        sh[tid] += t;
        __syncthreads();
    }
    if (i < N_NODES_C) off[i] = sh[tid] - v;  // exclusive
    if (tid == 1023) bsum[blockIdx.x] = sh[1023];
}

#define NSCAN_BLK 98  // ceil(100000/1024)

__global__ void scan2_k(int* __restrict__ bsum) {
    __shared__ int sh[128];
    int tid = threadIdx.x;
    int v = (tid < NSCAN_BLK) ? bsum[tid] : 0;
    sh[tid] = v;
    __syncthreads();
    for (int d = 1; d < 128; d <<= 1) {
        int t = (tid >= d) ? sh[tid - d] : 0;
        __syncthreads();
        sh[tid] += t;
        __syncthreads();
    }
    if (tid < NSCAN_BLK) bsum[tid] = sh[tid] - v;  // exclusive
}

__global__ void scan3_k(int* __restrict__ off, const int* __restrict__ bsum) {
    int i = blockIdx.x * 1024 + threadIdx.x;
    if (i < N_NODES_C) off[i] += bsum[blockIdx.x];
}

// place: off becomes end-cursor; after completion off[i] = start of node i+1
__global__ void place_k(const int* __restrict__ ei, int* __restrict__ off,
                        int* __restrict__ ssrc) {
    int e = blockIdx.x * 256 + threadIdx.x;
    if (e < N_EDGES_C) {
        int d = ei[N_EDGES_C + e];
        int p = atomicAdd(&off[d], 1);
        ssrc[p] = ei[e];
    }
}

// z1[i] = bf16(relu(y[i] + sum_{e:dst=i} y[src_e] + b1a)); 4 nodes/block, 64 lanes/node
__global__ void gather_relu_k(const short* __restrict__ y, const int* __restrict__ off,
                              const int* __restrict__ ssrc, const float* __restrict__ b1a,
                              short* __restrict__ z1) {
    int node = blockIdx.x * 4 + (threadIdx.x >> 6);
    if (node >= N_NODES_C) return;
    int t = threadIdx.x & 63;
    const int col = t * 8;
    int beg = (node == 0) ? 0 : off[node - 1];
    int end = off[node];
    s16x8 own = *(const s16x8*)(y + (size_t)node * DC + col);
    float acc[8];
#pragma unroll
    for (int q = 0; q < 8; ++q) acc[q] = bf2f(own[q]);
    int j = beg;
    for (; j + 2 <= end; j += 2) {
        int s0 = ssrc[j];
        int s1 = ssrc[j + 1];
        s16x8 r0 = *(const s16x8*)(y + (size_t)s0 * DC + col);
        s16x8 r1 = *(const s16x8*)(y + (size_t)s1 * DC + col);
#pragma unroll
        for (int q = 0; q < 8; ++q) acc[q] += bf2f(r0[q]) + bf2f(r1[q]);
    }
    if (j < end) {
        int s0 = ssrc[j];
        s16x8 r0 = *(const s16x8*)(y + (size_t)s0 * DC + col);
#pragma unroll
        for (int q = 0; q < 8; ++q) acc[q] += bf2f(r0[q]);
    }
    f32x4 bv0 = *(const f32x4*)(b1a + col);
    f32x4 bv1 = *(const f32x4*)(b1a + col + 4);
    s16x8 o;
    o[0] = f2bf(fmaxf(acc[0] + bv0.x, 0.f));
    o[1] = f2bf(fmaxf(acc[1] + bv0.y, 0.f));
    o[2] = f2bf(fmaxf(acc[2] + bv0.z, 0.f));
    o[3] = f2bf(fmaxf(acc[3] + bv0.w, 0.f));
    o[4] = f2bf(fmaxf(acc[4] + bv1.x, 0.f));
    o[5] = f2bf(fmaxf(acc[5] + bv1.y, 0.f));
    o[6] = f2bf(fmaxf(acc[6] + bv1.z, 0.f));
    o[7] = f2bf(fmaxf(acc[7] + bv1.w, 0.f));
    *(s16x8*)(z1 + (size_t)node * DC + col) = o;
}

// ---------------- scalar tail ----------------

__global__ void edge_scalar(const int* __restrict__ ei, const float* __restrict__ s,
                            float* __restrict__ aggs) {
    int e = blockIdx.x * 256 + threadIdx.x;
    if (e < N_EDGES_C) atomicAdd(&aggs[ei[N_EDGES_C + e]], s[ei[e]]);
}

__global__ void node_pool(const float* __restrict__ s, const float* __restrict__ aggs,
                          const int* __restrict__ batch, const float* __restrict__ b2a,
                          float* __restrict__ gsum, float* __restrict__ gcnt) {
    __shared__ float ls[NG], lc[NG];
    int t = threadIdx.x;
    if (t < NG) { ls[t] = 0.f; lc[t] = 0.f; }
    __syncthreads();
    int i = blockIdx.x * 256 + t;
    if (i < N_NODES_C) {
        float z2 = fmaxf(aggs[i] + s[i] + b2a[0], 0.0f);
        int g = batch[i];
        atomicAdd(&ls[g], z2);
        atomicAdd(&lc[g], 1.0f);
    }
    __syncthreads();
    if (t < NG && lc[t] != 0.f) {
        atomicAdd(&gsum[t], ls[t]);
        atomicAdd(&gcnt[t], lc[t]);
    }
}

__global__ void finalize_k(const float* gsum, const float* gcnt, const float* w2b,
                           const float* b2b, float* out) {
    int g = threadIdx.x;
    if (g < NG) {
        float c = fmaxf(gcnt[g], 1.0f);
        out[g] = gsum[g] / c * w2b[0] + b2b[0];
    }
}

// ---------------- GEMM ----------------
// Round-8 structure (best measured): 128x128 tile, BK=32, single-buffered
// 16KB LDS, 2-barrier loop. New: XOR chunk-swizzle c' = c ^ ((row>>1)&3)
// (source-side for gload_lds, write-side for f32 path, matched on frag reads)
// kills round-8's 8-way frag-read conflict (9.6e6/dispatch). MINW template:
// GEMM0 (ASRC0, has areg) stays at 3 waves/EU; GEMM1 (ASRC1, ~108 regs) gets
// 4 waves/EU for occupancy.
// ASRC 0: A f32, reg-staged + fused f32->bf16. ASRC 1: A bf16 via gload_lds.
// EPI 1: h = relu(A@W + bias); s_out[row] += h . w2a
// EPI 2: C = A@W -> bf16
#define BM 128
#define BN 128
#define BK 32
#define NKT (DC / BK)  // 16
#define NWG 3128       // 782 row tiles * 4 col tiles = 8 * 391
#define WPX 391

template <int ASRC, int EPI, int MINW>
__global__ __launch_bounds__(256, MINW) void gemm_k(const void* __restrict__ Ap,
                                                    const short* __restrict__ Bt,
                                                    const float* __restrict__ bias,
                                                    short* __restrict__ Cout,
                                                    const float* __restrict__ w2a,
                                                    float* __restrict__ s_out) {
    __shared__ alignas(16) short As[BM * BK];  // 8 KB
    __shared__ alignas(16) short Bs[BN * BK];  // 8 KB

    const int tid = threadIdx.x;
    // XCD-aware bijective remap: 3128 = 8*391
    const int bid = blockIdx.x;
    const int lin = (bid & 7) * WPX + (bid >> 3);
    const int brow = (lin >> 2) * BM;
    const int bcol = (lin & 3) * BN;

    const int w    = tid >> 6;       // wave 0..3
    const int lane = tid & 63;
    const int wr   = (w >> 1) * 64;  // wave row
    const int wc   = (w & 1) * 64;   // wave col
    const int lr   = lane & 15;
    const int lg   = lane >> 4;      // 0..3: data chunk this lane consumes
    const int lswz = (lr >> 1) & 3;  // read-side swizzle

    f32x4 acc[4][4] = {};

    // ---- staging geometry: row = 32 shorts = 4 chunks of 16B ----
    const int srow = lane >> 2;                          // 0..15
    const int scol = (((lane & 3) ^ ((srow >> 1) & 3)) * 8);  // swizzled src chunk

    // B: wave w stages rows bcol + w*32 + srow and +16
    const short* bg0 = Bt + (size_t)(bcol + w * 32 + srow) * DC + scol;
    const short* bg1 = bg0 + (size_t)16 * DC;
    short* bl0 = &Bs[(w * 32) * BK];
    short* bl1 = &Bs[(w * 32 + 16) * BK];

    // A staging
    const short* ag0 = nullptr;
    const short* ag1 = nullptr;
    short* al0 = nullptr;
    short* al1 = nullptr;
    const float* axsrc = nullptr;
    int awoff0 = 0, awoff1 = 0;
    const int rAl = tid >> 1;  // f32 path: LDS row this thread stages (0..127)
    if constexpr (ASRC == 1) {
        int ar0 = brow + w * 32 + srow;
        int ar1 = ar0 + 16;
        if (ar0 >= N_NODES_C) ar0 = N_NODES_C - 1;  // clamp; stores guarded
        if (ar1 >= N_NODES_C) ar1 = N_NODES_C - 1;
        ag0 = (const short*)Ap + (size_t)ar0 * DC + scol;
        ag1 = (const short*)Ap + (size_t)ar1 * DC + scol;
        al0 = &As[(w * 32) * BK];
        al1 = &As[(w * 32 + 16) * BK];
    } else {
        int r = brow + rAl;
        if (r >= N_NODES_C) r = N_NODES_C - 1;
        axsrc = (const float*)Ap + (size_t)r * DC + (tid & 1) * 16;
        const int rswz = (rAl >> 1) & 3;
        awoff0 = rAl * BK + ((((tid & 1) * 2 + 0) ^ rswz) * 8);
        awoff1 = rAl * BK + ((((tid & 1) * 2 + 1) ^ rswz) * 8);
    }

    f32x4 areg[4];
    if constexpr (ASRC == 0) {
#pragma unroll
        for (int q = 0; q < 4; ++q) areg[q] = *(const f32x4*)(axsrc + q * 4);  // tile 0
    }

    for (int kt = 0; kt < NKT; ++kt) {
        const int k0 = kt * BK;
        __syncthreads();  // all waves done reading LDS from previous tile
        if constexpr (ASRC == 1) {
            gload16(ag0 + k0, al0);
            gload16(ag1 + k0, al1);
        } else {
            s16x8 c0, c1;
            c0[0] = f2bf(areg[0].x); c0[1] = f2bf(areg[0].y);
            c0[2] = f2bf(areg[0].z); c0[3] = f2bf(areg[0].w);
            c0[4] = f2bf(areg[1].x); c0[5] = f2bf(areg[1].y);
            c0[6] = f2bf(areg[1].z); c0[7] = f2bf(areg[1].w);
            c1[0] = f2bf(areg[2].x); c1[1] = f2bf(areg[2].y);
            c1[2] = f2bf(areg[2].z); c1[3] = f2bf(areg[2].w);
            c1[4] = f2bf(areg[3].x); c1[5] = f2bf(areg[3].y);
            c1[6] = f2bf(areg[3].z); c1[7] = f2bf(areg[3].w);
            *(s16x8*)&As[awoff0] = c0;
            *(s16x8*)&As[awoff1] = c1;
        }
        gload16(bg0 + k0, bl0);
        gload16(bg1 + k0, bl1);
        __syncthreads();  // drains vmcnt+lgkmcnt: tile kt fully in LDS

        if constexpr (ASRC == 0) {
            if (kt + 1 < NKT) {  // next f32 A slab: lands during MFMA below
#pragma unroll
                for (int q = 0; q < 4; ++q)
                    areg[q] = *(const f32x4*)(axsrc + (kt + 1) * BK + q * 4);
            }
        }

        s16x8 af[4], bfr[4];
#pragma unroll
        for (int mi = 0; mi < 4; ++mi)
            af[mi] = *(const s16x8*)&As[(wr + mi * 16 + lr) * BK + ((lg ^ lswz) * 8)];
#pragma unroll
        for (int ni = 0; ni < 4; ++ni)
            bfr[ni] = *(const s16x8*)&Bs[(wc + ni * 16 + lr) * BK + ((lg ^ lswz) * 8)];
        __builtin_amdgcn_s_setprio(1);
#pragma unroll
        for (int mi = 0; mi < 4; ++mi)
#pragma unroll
            for (int ni = 0; ni < 4; ++ni)
                acc[mi][ni] = __builtin_amdgcn_mfma_f32_16x16x32_bf16(af[mi], bfr[ni],
                                                                      acc[mi][ni], 0, 0, 0);
        __builtin_amdgcn_s_setprio(0);
    }

    // C/D layout: col = lane&15, row = (lane>>4)*4 + reg
    const int rb = brow + wr + lg * 4;
    const int cb = bcol + wc + lr;

    if constexpr (EPI == 2) {
#pragma unroll
        for (int mi = 0; mi < 4; ++mi) {
#pragma unroll
            for (int r = 0; r < 4; ++r) {
                int row = rb + mi * 16 + r;
                if (row < N_NODES_C) {
#pragma unroll
                    for (int ni = 0; ni < 4; ++ni)
                        Cout[(size_t)row * DC + cb + ni * 16] = f2bf(acc[mi][ni][r]);
                }
            }
        }
    } else {
        float bv[4], wv[4];
#pragma unroll
        for (int ni = 0; ni < 4; ++ni) {
            bv[ni] = bias[cb + ni * 16];
            wv[ni] = w2a[cb + ni * 16];
        }
#pragma unroll
        for (int mi = 0; mi < 4; ++mi) {
#pragma unroll
            for (int r = 0; r < 4; ++r) {
                float sum = 0.f;
#pragma unroll
                for (int ni = 0; ni < 4; ++ni) {
                    float v = fmaxf(acc[mi][ni][r] + bv[ni], 0.0f);
                    sum += v * wv[ni];
                }
#pragma unroll
                for (int off = 1; off < 16; off <<= 1) sum += __shfl_xor(sum, off, 64);
                int row = rb + mi * 16 + r;
                if (lr == 0 && row < N_NODES_C) atomicAdd(&s_out[row], sum);
            }
        }
    }
}

// ---------------- launch ----------------

extern "C" void kernel_launch(void* const* d_in, const int* in_sizes, int n_in,
                              void* d_out, int out_size, void* d_ws, size_t ws_size,
                              hipStream_t stream) {
    const float* x     = (const float*)d_in[0];
    const int*   ei    = (const int*)d_in[1];
    const int*   batch = (const int*)d_in[2];
    const float* W1a   = (const float*)d_in[3];
    const float* b1a   = (const float*)d_in[4];
    const float* W1b   = (const float*)d_in[5];
    const float* b1b   = (const float*)d_in[6];
    const float* W2a   = (const float*)d_in[7];
    const float* b2a   = (const float*)d_in[8];
    const float* W2b   = (const float*)d_in[9];
    const float* b2b   = (const float*)d_in[10];
    float* out = (float*)d_out;

    char* w = (char*)d_ws;
    short* z1   = (short*)(w);                  // 102,400,000
    short* y    = (short*)(w + 102400000);      // 102,400,000
    short* WT1  = (short*)(w + 204800000);      // 524,288
    short* WT2  = (short*)(w + 205324288);      // 524,288
    float* sbuf = (float*)(w + 205848576);      // 400,000
    float* aggs = (float*)(w + 206248576);      // 400,000
    int*   cnt  = (int*)  (w + 206648576);      // 400,000
    int*   offb = (int*)  (w + 207048576);      // 400,000
    int*   ssrc = (int*)  (w + 207448576);      // 600,000
    int*   bsum = (int*)  (w + 208048576);      // 512
    float* gsum = (float*)(w + 208049088);      // 256
    float* gcnt = (float*)(w + 208049344);      // 256

    zero_k<<<391, 256, 0, stream>>>(sbuf, aggs, cnt, gsum, gcnt);
    transpose_w2<<<dim3(16, 16, 2), 256, 0, stream>>>(W1a, W1b, WT1, WT2);

    // CSR build (independent of GEMM0)
    hist_k<<<586, 256, 0, stream>>>(ei, cnt);
    scan1_k<<<NSCAN_BLK, 1024, 0, stream>>>(cnt, offb, bsum);
    scan2_k<<<1, 128, 0, stream>>>(bsum);
    scan3_k<<<NSCAN_BLK, 1024, 0, stream>>>(offb, bsum);
    place_k<<<586, 256, 0, stream>>>(ei, offb, ssrc);

    // y = bf16(x) @ W1a  (f32 A, fused convert in staging)
    gemm_k<0, 2, 3><<<NWG, 256, 0, stream>>>(x, WT1, nullptr, y, nullptr, nullptr);
    // z1 = relu(y + agg(y) + b1a)
    gather_relu_k<<<25000, 256, 0, stream>>>(y, offb, ssrc, b1a, z1);
    // s = relu(z1 @ W1b + b1b) . W2a
    gemm_k<1, 1, 4><<<NWG, 256, 0, stream>>>(z1, WT2, b1b, nullptr, W2a, sbuf);

    edge_scalar<<<586, 256, 0, stream>>>(ei, sbuf, aggs);
    node_pool<<<391, 256, 0, stream>>>(sbuf, aggs, batch, b2a, gsum, gcnt);
    finalize_k<<<1, 64, 0, stream>>>(gsum, gcnt, W2b, b2b, out);
}